// Round 1
// baseline (1142.256 us; speedup 1.0000x reference)
//
#include <hip/hip_runtime.h>
#include <hip/hip_bf16.h>
#include <math.h>

#define B_  2
#define S_  2048
#define D_  1024
#define H_  16
#define DK_ 64

// ---------------------------------------------------------------------------
// NT GEMM: C[n][j] = sum_k A[n][k] * W[j][k]   (A: M x K, W: N x K, row-major)
// M = B*S = 4096, N = K = 1024. 64x64 output tile per block, BK=32.
// LDS tiles stored k-major [k][n] (stride 68) so the compute loop reads one
// float4 per operand per k (4 contiguous rows/cols) conflict-free.
// MODE 0: write head-major  buf[((b*H + h)*S + s)*DK + dk]   (h = blockIdx.x)
// MODE 1: write row-major   C[n*D + j]
// ---------------------------------------------------------------------------
template<int MODE>
__global__ __launch_bounds__(256)
void gemm_nt(const float* __restrict__ A, const float* __restrict__ W,
             float* __restrict__ C) {
  __shared__ __align__(16) float As[32][68];
  __shared__ __align__(16) float Ws[32][68];
  const int n0 = blockIdx.y * 64;
  const int j0 = blockIdx.x * 64;
  const int t  = threadIdx.x;
  const int tx = t & 15, ty = t >> 4;
  const int row = t >> 3;        // 0..31
  const int c4  = (t & 7) * 4;   // k offset 0..28

  float acc[4][4] = {{0.f,0.f,0.f,0.f},{0.f,0.f,0.f,0.f},
                     {0.f,0.f,0.f,0.f},{0.f,0.f,0.f,0.f}};

  for (int kb = 0; kb < D_; kb += 32) {
    __syncthreads();
#pragma unroll
    for (int rr = 0; rr < 2; ++rr) {
      const int r = row + rr * 32;
      float4 a = *(const float4*)&A[(size_t)(n0 + r) * D_ + kb + c4];
      As[c4+0][r] = a.x; As[c4+1][r] = a.y; As[c4+2][r] = a.z; As[c4+3][r] = a.w;
      float4 w = *(const float4*)&W[(size_t)(j0 + r) * D_ + kb + c4];
      Ws[c4+0][r] = w.x; Ws[c4+1][r] = w.y; Ws[c4+2][r] = w.z; Ws[c4+3][r] = w.w;
    }
    __syncthreads();
#pragma unroll
    for (int k = 0; k < 32; ++k) {
      float4 av = *(const float4*)&As[k][ty * 4];
      float4 wv = *(const float4*)&Ws[k][tx * 4];
      const float a_[4] = {av.x, av.y, av.z, av.w};
      const float w_[4] = {wv.x, wv.y, wv.z, wv.w};
#pragma unroll
      for (int i = 0; i < 4; ++i)
#pragma unroll
        for (int j = 0; j < 4; ++j)
          acc[i][j] = fmaf(a_[i], w_[j], acc[i][j]);
    }
  }

#pragma unroll
  for (int i = 0; i < 4; ++i) {
    const int n = n0 + ty * 4 + i;
    float4 v = make_float4(acc[i][0], acc[i][1], acc[i][2], acc[i][3]);
    if (MODE == 0) {
      const int b = n >> 11;          // n / S_
      const int s = n & (S_ - 1);
      const int h = j0 >> 6;          // one head per 64-wide column tile
      *(float4*)&C[((size_t)((b * H_ + h) * S_ + s)) * DK_ + tx * 4] = v;
    } else {
      *(float4*)&C[(size_t)n * D_ + j0 + tx * 4] = v;
    }
  }
}

// ---------------------------------------------------------------------------
// Per-head RMSNorm (over DK=64) + RoPE, in-place on head-major Q and K.
// One wave per (b,h,s) row; lane = dk index. blockIdx.y: 0 = Q, 1 = K.
// ---------------------------------------------------------------------------
__global__ __launch_bounds__(256)
void rmsnorm_rope(float* __restrict__ Qb, float* __restrict__ Kb,
                  const float* __restrict__ qw, const float* __restrict__ kw) {
  const int lane = threadIdx.x & 63;
  const int row  = blockIdx.x * 4 + (threadIdx.x >> 6);  // (b*H + h)*S + s
  float* buf = blockIdx.y ? Kb : Qb;
  const float* w = blockIdx.y ? kw : qw;
  const int s = row & (S_ - 1);

  float x = buf[(size_t)row * DK_ + lane];
  float ss = x * x;
#pragma unroll
  for (int m = 1; m < 64; m <<= 1) ss += __shfl_xor(ss, m);
  const float rms = rsqrtf(ss * (1.0f / DK_) + 1e-10f);
  const float xn  = w[lane] * x * rms;

  // RoPE: inv_freq[j] = 500000^(-j/32), j = lane % 32
  const int j = lane & 31;
  const float inv  = expf(-(float)j * (13.122363377404328f / 32.0f)); // ln(5e5)
  const float freq = (float)s * inv;
  const float c  = cosf(freq);
  const float sn = sinf(freq);
  float rot = __shfl_xor(xn, 32);
  rot = (lane < 32) ? -rot : rot;
  buf[(size_t)row * DK_ + lane] = xn * c + rot * sn;
}

// ---------------------------------------------------------------------------
// Causal flash attention. One block per (q-tile of 64, head). fp32.
// S = Q K^T * 0.125 (online softmax, running m/l per row), O += P V.
// Thread (ty,tx) owns rows ty*4..+3, cols tx*4..+3 of every 64x64 tile.
// ---------------------------------------------------------------------------
__global__ __launch_bounds__(256)
void flash_attn(const float* __restrict__ Q, const float* __restrict__ K,
                const float* __restrict__ V, float* __restrict__ O) {
  __shared__ __align__(16) float Qs[64][68];  // [d][r]
  __shared__ __align__(16) float Ks[64][68];  // [d][c]
  __shared__ __align__(16) float Vs[64][68];  // [k][d]
  __shared__ __align__(16) float Ps[64][68];  // [k][r]
  const int qt = blockIdx.x, bh = blockIdx.y;
  const int t  = threadIdx.x, tx = t & 15, ty = t >> 4;
  const size_t base = (size_t)bh * S_ * DK_;
  const float* Qh = Q + base;
  const float* Kh = K + base;
  const float* Vh = V + base;

  // Load Q tile (contiguous 64x64 block) transposed into Qs[d][r].
  {
    const int e = t * 4;
#pragma unroll
    for (int ii = 0; ii < 4; ++ii) {
      const int idx = e + ii * 1024;
      const int r = idx >> 6, d = idx & 63;
      float4 v = *(const float4*)&Qh[(size_t)qt * 4096 + idx];
      Qs[d+0][r] = v.x; Qs[d+1][r] = v.y; Qs[d+2][r] = v.z; Qs[d+3][r] = v.w;
    }
  }

  float o_[4][4] = {{0.f,0.f,0.f,0.f},{0.f,0.f,0.f,0.f},
                    {0.f,0.f,0.f,0.f},{0.f,0.f,0.f,0.f}};
  float m_[4], l_[4];
#pragma unroll
  for (int i = 0; i < 4; ++i) { m_[i] = -INFINITY; l_[i] = 0.f; }

  for (int kt = 0; kt <= qt; ++kt) {
    __syncthreads();   // previous iteration's PV reads of Vs/Ps are done
    {
      const int e = t * 4;
#pragma unroll
      for (int ii = 0; ii < 4; ++ii) {
        const int idx = e + ii * 1024;
        const int r = idx >> 6, d = idx & 63;
        float4 kv = *(const float4*)&Kh[(size_t)kt * 4096 + idx];
        Ks[d+0][r] = kv.x; Ks[d+1][r] = kv.y; Ks[d+2][r] = kv.z; Ks[d+3][r] = kv.w;
        float4 vv = *(const float4*)&Vh[(size_t)kt * 4096 + idx];
        *(float4*)&Vs[r][d] = vv;
      }
    }
    __syncthreads();

    // S = Q K^T
    float s_[4][4] = {{0.f,0.f,0.f,0.f},{0.f,0.f,0.f,0.f},
                      {0.f,0.f,0.f,0.f},{0.f,0.f,0.f,0.f}};
#pragma unroll 8
    for (int d = 0; d < 64; ++d) {
      float4 qv = *(const float4*)&Qs[d][ty * 4];
      float4 kv = *(const float4*)&Ks[d][tx * 4];
      const float q_[4] = {qv.x, qv.y, qv.z, qv.w};
      const float k_[4] = {kv.x, kv.y, kv.z, kv.w};
#pragma unroll
      for (int i = 0; i < 4; ++i)
#pragma unroll
        for (int j = 0; j < 4; ++j)
          s_[i][j] = fmaf(q_[i], k_[j], s_[i][j]);
    }

    // scale + causal mask (only diagonal tile needs masking)
#pragma unroll
    for (int i = 0; i < 4; ++i)
#pragma unroll
      for (int j = 0; j < 4; ++j) {
        s_[i][j] *= 0.125f;
        if (kt == qt && (tx * 4 + j) > (ty * 4 + i)) s_[i][j] = -INFINITY;
      }

    // online softmax across the 16-lane tx group
#pragma unroll
    for (int i = 0; i < 4; ++i) {
      float mx = fmaxf(fmaxf(s_[i][0], s_[i][1]), fmaxf(s_[i][2], s_[i][3]));
#pragma unroll
      for (int mm = 1; mm < 16; mm <<= 1) mx = fmaxf(mx, __shfl_xor(mx, mm));
      const float mn = fmaxf(m_[i], mx);
      const float alpha = __expf(m_[i] - mn);  // m_=-inf first pass -> 0
      float sum = 0.f;
#pragma unroll
      for (int j = 0; j < 4; ++j) {
        const float p = __expf(s_[i][j] - mn);
        s_[i][j] = p;
        sum += p;
      }
#pragma unroll
      for (int mm = 1; mm < 16; mm <<= 1) sum += __shfl_xor(sum, mm);
      l_[i] = l_[i] * alpha + sum;
      m_[i] = mn;
#pragma unroll
      for (int j = 0; j < 4; ++j) o_[i][j] *= alpha;
    }

    // stage P transposed: Ps[k][r]
#pragma unroll
    for (int i = 0; i < 4; ++i)
#pragma unroll
      for (int j = 0; j < 4; ++j)
        Ps[tx * 4 + j][ty * 4 + i] = s_[i][j];
    __syncthreads();

    // O += P V
#pragma unroll 8
    for (int k = 0; k < 64; ++k) {
      float4 pv = *(const float4*)&Ps[k][ty * 4];
      float4 vv = *(const float4*)&Vs[k][tx * 4];
      const float p_[4] = {pv.x, pv.y, pv.z, pv.w};
      const float v_[4] = {vv.x, vv.y, vv.z, vv.w};
#pragma unroll
      for (int i = 0; i < 4; ++i)
#pragma unroll
        for (int j = 0; j < 4; ++j)
          o_[i][j] = fmaf(p_[i], v_[j], o_[i][j]);
    }
  }

  // epilogue: O /= l, write [b, s, h, d] so final GEMM reads row-major (B*S, D)
  const int b = bh >> 4, h = bh & 15;
#pragma unroll
  for (int i = 0; i < 4; ++i) {
    const int srow = qt * 64 + ty * 4 + i;
    const float linv = 1.0f / l_[i];
    float4 v = make_float4(o_[i][0] * linv, o_[i][1] * linv,
                           o_[i][2] * linv, o_[i][3] * linv);
    *(float4*)&O[((size_t)(b * S_ + srow) * H_ + h) * DK_ + tx * 4] = v;
  }
}

// ---------------------------------------------------------------------------
extern "C" void kernel_launch(void* const* d_in, const int* in_sizes, int n_in,
                              void* d_out, int out_size, void* d_ws, size_t ws_size,
                              hipStream_t stream) {
  (void)in_sizes; (void)n_in; (void)out_size; (void)ws_size;
  const float* q  = (const float*)d_in[0];
  const float* k  = (const float*)d_in[1];
  const float* v  = (const float*)d_in[2];
  const float* Wq = (const float*)d_in[3];
  const float* Wk = (const float*)d_in[4];
  const float* Wv = (const float*)d_in[5];
  const float* Wo = (const float*)d_in[6];
  const float* qw = (const float*)d_in[7];
  const float* kw = (const float*)d_in[8];
  float* out = (float*)d_out;

  const size_t NE = (size_t)B_ * H_ * S_ * DK_;  // 4,194,304 floats = 16 MB
  float* Qb = (float*)d_ws;       // [b][h][s][dk]
  float* Kb = Qb + NE;
  float* Vb = Kb + NE;
  float* Ab = Vb + NE;            // [b][s][h][dk] == row-major (B*S, D)

  const dim3 gproj(D_ / 64, (B_ * S_) / 64);   // (16, 64)
  gemm_nt<0><<<gproj, 256, 0, stream>>>(q, Wq, Qb);
  gemm_nt<0><<<gproj, 256, 0, stream>>>(k, Wk, Kb);
  gemm_nt<0><<<gproj, 256, 0, stream>>>(v, Wv, Vb);

  rmsnorm_rope<<<dim3(B_ * H_ * S_ / 4, 2), 256, 0, stream>>>(Qb, Kb, qw, kw);

  flash_attn<<<dim3(S_ / 64, B_ * H_), 256, 0, stream>>>(Qb, Kb, Vb, Ab);

  gemm_nt<1><<<gproj, 256, 0, stream>>>(Ab, Wo, out);
}

// Round 2
// 344.798 us; speedup vs baseline: 3.3128x; 3.3128x over previous
//
#include <hip/hip_runtime.h>
#include <hip/hip_bf16.h>
#include <math.h>

#define B_  2
#define S_  2048
#define D_  1024
#define H_  16
#define DK_ 64

typedef __attribute__((ext_vector_type(8))) short bf16x8;   // 8 bf16 = 4 VGPRs
typedef __attribute__((ext_vector_type(4))) float f32x4;

#define MFMA_BF16(a, b, c) __builtin_amdgcn_mfma_f32_16x16x32_bf16((a), (b), (c), 0, 0, 0)

// fp32 -> bf16 round-to-nearest-even
__device__ __forceinline__ unsigned short f2bf(float f) {
  unsigned int u = __float_as_uint(f);
  u += 0x7FFFu + ((u >> 16) & 1u);
  return (unsigned short)(u >> 16);
}

// async global->LDS, 16 B per lane; LDS dest = wave-uniform base + lane*16
__device__ __forceinline__ void gl_lds16(const void* g, void* l) {
  __builtin_amdgcn_global_load_lds(
      (const __attribute__((address_space(1))) void*)g,
      (__attribute__((address_space(3))) void*)l, 16, 0, 0);
}

// ---------------------------------------------------------------------------
// fp32 -> bf16 conversion for q,k,v and the four weight matrices.
// ---------------------------------------------------------------------------
__global__ __launch_bounds__(256)
void cvt_bf16(const float* __restrict__ q, const float* __restrict__ k,
              const float* __restrict__ v, const float* __restrict__ wq,
              const float* __restrict__ wk, const float* __restrict__ wv,
              const float* __restrict__ wo,
              unsigned short* __restrict__ qb, unsigned short* __restrict__ kb,
              unsigned short* __restrict__ vb, unsigned short* __restrict__ wqb,
              unsigned short* __restrict__ wkb, unsigned short* __restrict__ wvb,
              unsigned short* __restrict__ wob) {
  const float* src; unsigned short* dst; int n;
  switch (blockIdx.y) {
    case 0: src = q;  dst = qb;  n = B_ * S_ * D_; break;
    case 1: src = k;  dst = kb;  n = B_ * S_ * D_; break;
    case 2: src = v;  dst = vb;  n = B_ * S_ * D_; break;
    case 3: src = wq; dst = wqb; n = D_ * D_; break;
    case 4: src = wk; dst = wkb; n = D_ * D_; break;
    case 5: src = wv; dst = wvb; n = D_ * D_; break;
    default: src = wo; dst = wob; n = D_ * D_; break;
  }
  const int i = (blockIdx.x * 256 + threadIdx.x) * 4;
  if (i >= n) return;
  float4 val = *(const float4*)&src[i];
  ushort4 r4;
  r4.x = f2bf(val.x); r4.y = f2bf(val.y); r4.z = f2bf(val.z); r4.w = f2bf(val.w);
  *(ushort4*)&dst[i] = r4;
}

// ---------------------------------------------------------------------------
// MFMA NT GEMM: C[m][n] = sum_k A[m][k] * W[n][k], A: 4096x1024, W: 1024x1024.
// 128x128 tile, BK=32, 4 waves (2x2), 4x4 MFMA tiles per wave.
// Double-buffered LDS staged via global_load_lds width=16 (grid = 256 blocks
// = 1 block/CU, so prefetch into buf^1 overlaps compute to hide load latency).
// OUTMODE 0: fp32 head-major [b][h][s][dk]   (Q,K before RMSNorm)
// OUTMODE 1: bf16 head-major                 (V)
// OUTMODE 2: fp32 row-major [m][n]           (final output)
// ---------------------------------------------------------------------------
template<int OUTMODE>
__global__ __launch_bounds__(256)
void gemm_bt(const unsigned short* __restrict__ A, const unsigned short* __restrict__ W,
             void* __restrict__ out) {
  __shared__ unsigned short As[2][128 * 32];
  __shared__ unsigned short Bs[2][128 * 32];
  const int t = threadIdx.x, lane = t & 63, wave = t >> 6;
  const int l16 = lane & 15, quad = lane >> 4;
  const int wm = wave >> 1, wn = wave & 1;
  const int m0 = blockIdx.y * 128, j0 = blockIdx.x * 128;

  f32x4 acc[4][4];
#pragma unroll
  for (int i = 0; i < 4; ++i)
#pragma unroll
    for (int j = 0; j < 4; ++j) acc[i][j] = (f32x4)(0.0f);

  auto stage = [&](int kb, int buf) {
#pragma unroll
    for (int i = 0; i < 2; ++i) {
      const int c  = (wave * 2 + i) * 64 + lane;  // 16B chunk id, 0..511
      const int r  = c >> 2;                      // tile row 0..127
      const int co = (c & 3) * 8;                 // ushort offset within 32-wide row
      gl_lds16(&A[(size_t)(m0 + r) * D_ + kb + co], &As[buf][(wave * 2 + i) * 512]);
      gl_lds16(&W[(size_t)(j0 + r) * D_ + kb + co], &Bs[buf][(wave * 2 + i) * 512]);
    }
  };

  stage(0, 0);
  for (int kb = 0; kb < D_; kb += 32) {
    const int buf = (kb >> 5) & 1;
    __syncthreads();                 // staged buf ready (vmcnt drained at barrier)
    if (kb + 32 < D_) stage(kb + 32, buf ^ 1);

    bf16x8 af[4], bfr[4];
#pragma unroll
    for (int mi = 0; mi < 4; ++mi)
      af[mi] = *(const bf16x8*)&As[buf][(wm * 64 + mi * 16 + l16) * 32 + quad * 8];
#pragma unroll
    for (int ni = 0; ni < 4; ++ni)
      bfr[ni] = *(const bf16x8*)&Bs[buf][(wn * 64 + ni * 16 + l16) * 32 + quad * 8];
#pragma unroll
    for (int mi = 0; mi < 4; ++mi)
#pragma unroll
      for (int ni = 0; ni < 4; ++ni)
        acc[mi][ni] = MFMA_BF16(af[mi], bfr[ni], acc[mi][ni]);
  }

  // epilogue: C/D layout col = lane&15, row = quad*4 + reg
#pragma unroll
  for (int mi = 0; mi < 4; ++mi) {
    const int rowb = m0 + wm * 64 + mi * 16 + quad * 4;
#pragma unroll
    for (int ni = 0; ni < 4; ++ni) {
      const int col = j0 + wn * 64 + ni * 16 + l16;
#pragma unroll
      for (int r = 0; r < 4; ++r) {
        const float val = acc[mi][ni][r];
        const int rr = rowb + r;
        if (OUTMODE == 2) {
          ((float*)out)[(size_t)rr * D_ + col] = val;
        } else {
          const int b = rr >> 11, s = rr & (S_ - 1);
          const int h = col >> 6, dk = col & 63;
          const size_t idx = ((size_t)(b * H_ + h) * S_ + s) * DK_ + dk;
          if (OUTMODE == 0) ((float*)out)[idx] = val;
          else              ((unsigned short*)out)[idx] = f2bf(val);
        }
      }
    }
  }
}

// ---------------------------------------------------------------------------
// Per-head RMSNorm + RoPE: fp32 head-major in -> bf16 head-major out.
// One wave per (b,h,s) row of 64. blockIdx.y: 0 = Q, 1 = K.
// ---------------------------------------------------------------------------
__global__ __launch_bounds__(256)
void rmsnorm_rope(const float* __restrict__ Qh, const float* __restrict__ Kh,
                  unsigned short* __restrict__ Qb, unsigned short* __restrict__ Kb,
                  const float* __restrict__ qw, const float* __restrict__ kw) {
  const int lane = threadIdx.x & 63;
  const int row  = blockIdx.x * 4 + (threadIdx.x >> 6);
  const float* src = blockIdx.y ? Kh : Qh;
  const float* w   = blockIdx.y ? kw : qw;
  unsigned short* dst = blockIdx.y ? Kb : Qb;
  const int s = row & (S_ - 1);

  float x = src[(size_t)row * DK_ + lane];
  float ss = x * x;
#pragma unroll
  for (int m = 1; m < 64; m <<= 1) ss += __shfl_xor(ss, m);
  const float rms = rsqrtf(ss * (1.0f / DK_) + 1e-10f);
  const float xn  = w[lane] * x * rms;

  const int j = lane & 31;
  const float inv  = expf(-(float)j * (13.122363377404328f / 32.0f)); // ln(5e5)
  const float freq = (float)s * inv;
  const float c  = cosf(freq);
  const float sn = sinf(freq);
  float rot = __shfl_xor(xn, 32);
  rot = (lane < 32) ? -rot : rot;
  dst[(size_t)row * DK_ + lane] = f2bf(xn * c + rot * sn);
}

// ---------------------------------------------------------------------------
// V transpose per head: bf16 [bh][s][dk] -> bf16 [bh][dk][s]
// (so PV B-fragments in flash are contiguous 16B ds_reads)
// ---------------------------------------------------------------------------
__global__ __launch_bounds__(256)
void transpose_v(const unsigned short* __restrict__ Vh, unsigned short* __restrict__ Vt) {
  __shared__ unsigned short tile[64 * 65];  // stride 65: conflict-free column reads
  const int bh = blockIdx.y, s0 = blockIdx.x * 64;
  const int t = threadIdx.x;
  const size_t base = (size_t)bh * S_ * DK_;
#pragma unroll
  for (int i = 0; i < 2; ++i) {
    const int c = i * 256 + t;
    const int r = c >> 3, co = (c & 7) * 8;
    unsigned short tmp[8];
    *(bf16x8*)tmp = *(const bf16x8*)&Vh[base + (size_t)(s0 + r) * DK_ + co];
#pragma unroll
    for (int jj = 0; jj < 8; ++jj) tile[r * 65 + co + jj] = tmp[jj];
  }
  __syncthreads();
#pragma unroll
  for (int i = 0; i < 2; ++i) {
    const int c = i * 256 + t;
    const int dk = c >> 3, so = (c & 7) * 8;
    unsigned short tmp[8];
#pragma unroll
    for (int jj = 0; jj < 8; ++jj) tmp[jj] = tile[(so + jj) * 65 + dk];
    *(bf16x8*)&Vt[(size_t)bh * DK_ * S_ + (size_t)dk * S_ + s0 + so] = *(bf16x8*)tmp;
  }
}

// ---------------------------------------------------------------------------
// MFMA flash attention (bf16 inputs, fp32 online softmax).
// Block = 4 waves, Q-tile 128 rows (wave w owns rows w*32..+31, Q in regs),
// K-tile 64. LDS rows stride 72 ushorts (144 B) -> 2-way bank aliasing (free).
// P round-trips LDS: C-layout regs -> bf16 Ps[m][kv] -> A-operand fragments.
// ---------------------------------------------------------------------------
__global__ __launch_bounds__(256)
void flash_mfma(const unsigned short* __restrict__ Q, const unsigned short* __restrict__ K,
                const unsigned short* __restrict__ Vt, unsigned short* __restrict__ Oa) {
  __shared__ unsigned short Ks[64 * 72];    // [kv][dk]
  __shared__ unsigned short Vs[64 * 72];    // [dk][kv]
  __shared__ unsigned short Ps[128 * 72];   // [m][kv]
  const int qt = blockIdx.x, bh = blockIdx.y;
  const int t = threadIdx.x, lane = t & 63, wave = t >> 6;
  const int l16 = lane & 15, quad = lane >> 4;
  const size_t hb = (size_t)bh * S_ * DK_;
  const unsigned short* Qh  = Q + hb;
  const unsigned short* Kh  = K + hb;
  const unsigned short* Vth = Vt + hb;      // [dk][s]

  // Q fragments in registers: A[m = lane&15][k = quad*8+j], k split in 2x32
  bf16x8 qf[2][2];
#pragma unroll
  for (int mi = 0; mi < 2; ++mi)
#pragma unroll
    for (int ks = 0; ks < 2; ++ks)
      qf[mi][ks] = *(const bf16x8*)
        &Qh[(size_t)(qt * 128 + wave * 32 + mi * 16 + l16) * DK_ + ks * 32 + quad * 8];

  f32x4 o[2][4];
  float mrow[2][4], lrow[2][4];
#pragma unroll
  for (int mi = 0; mi < 2; ++mi)
#pragma unroll
    for (int r = 0; r < 4; ++r) { mrow[mi][r] = -INFINITY; lrow[mi][r] = 0.f; }
#pragma unroll
  for (int mi = 0; mi < 2; ++mi)
#pragma unroll
    for (int ni = 0; ni < 4; ++ni) o[mi][ni] = (f32x4)(0.0f);

  const int nkt = 2 * qt + 2;
  for (int kt = 0; kt < nkt; ++kt) {
    __syncthreads();  // prev iter's reads of Ks/Vs/Ps done
#pragma unroll
    for (int i = 0; i < 2; ++i) {
      const int c = i * 256 + t;
      const int r = c >> 3, co = (c & 7) * 8;
      *(bf16x8*)&Ks[r * 72 + co] = *(const bf16x8*)&Kh[(size_t)(kt * 64 + r) * DK_ + co];
      *(bf16x8*)&Vs[r * 72 + co] = *(const bf16x8*)&Vth[(size_t)r * S_ + kt * 64 + co];
    }
    __syncthreads();

    // S = Q K^T
    f32x4 sv[2][4];
#pragma unroll
    for (int mi = 0; mi < 2; ++mi)
#pragma unroll
      for (int ni = 0; ni < 4; ++ni) sv[mi][ni] = (f32x4)(0.0f);
#pragma unroll
    for (int ks = 0; ks < 2; ++ks) {
      bf16x8 bk[4];
#pragma unroll
      for (int ni = 0; ni < 4; ++ni)
        bk[ni] = *(const bf16x8*)&Ks[(ni * 16 + l16) * 72 + ks * 32 + quad * 8];
#pragma unroll
      for (int mi = 0; mi < 2; ++mi)
#pragma unroll
        for (int ni = 0; ni < 4; ++ni)
          sv[mi][ni] = MFMA_BF16(qf[mi][ks], bk[ni], sv[mi][ni]);
    }

    const bool diag = (kt >= 2 * qt);
    // online softmax; rows per lane: row = wave*32 + mi*16 + quad*4 + r
#pragma unroll
    for (int mi = 0; mi < 2; ++mi) {
#pragma unroll
      for (int r = 0; r < 4; ++r) {
        const int rowg = qt * 128 + wave * 32 + mi * 16 + quad * 4 + r;
        float mx = -3.0e38f;
#pragma unroll
        for (int ni = 0; ni < 4; ++ni) {
          float vsc = sv[mi][ni][r] * 0.125f;
          if (diag && (kt * 64 + ni * 16 + l16) > rowg) vsc = -INFINITY;
          sv[mi][ni][r] = vsc;
          mx = fmaxf(mx, vsc);
        }
#pragma unroll
        for (int mm = 1; mm < 16; mm <<= 1) mx = fmaxf(mx, __shfl_xor(mx, mm));
        const float mn = fmaxf(mrow[mi][r], mx);
        const float alpha = __expf(mrow[mi][r] - mn);  // -inf first pass -> 0
        mrow[mi][r] = mn;
        float sum = 0.f;
#pragma unroll
        for (int ni = 0; ni < 4; ++ni) {
          const float p = __expf(sv[mi][ni][r] - mn);
          sv[mi][ni][r] = p;
          sum += p;
        }
#pragma unroll
        for (int mm = 1; mm < 16; mm <<= 1) sum += __shfl_xor(sum, mm);
        lrow[mi][r] = lrow[mi][r] * alpha + sum;
#pragma unroll
        for (int ni = 0; ni < 4; ++ni) o[mi][ni][r] *= alpha;
      }
    }

    // P: C-layout regs -> bf16 LDS [m][kv]
#pragma unroll
    for (int mi = 0; mi < 2; ++mi)
#pragma unroll
      for (int ni = 0; ni < 4; ++ni)
#pragma unroll
        for (int r = 0; r < 4; ++r)
          Ps[(wave * 32 + mi * 16 + quad * 4 + r) * 72 + ni * 16 + l16] = f2bf(sv[mi][ni][r]);
    __syncthreads();

    // O += P V
#pragma unroll
    for (int ks = 0; ks < 2; ++ks) {
      bf16x8 ap[2], bv[4];
#pragma unroll
      for (int mi = 0; mi < 2; ++mi)
        ap[mi] = *(const bf16x8*)&Ps[(wave * 32 + mi * 16 + l16) * 72 + ks * 32 + quad * 8];
#pragma unroll
      for (int ni = 0; ni < 4; ++ni)
        bv[ni] = *(const bf16x8*)&Vs[(ni * 16 + l16) * 72 + ks * 32 + quad * 8];
#pragma unroll
      for (int mi = 0; mi < 2; ++mi)
#pragma unroll
        for (int ni = 0; ni < 4; ++ni)
          o[mi][ni] = MFMA_BF16(ap[mi], bv[ni], o[mi][ni]);
    }
  }

  // epilogue: O /= l, write bf16 [b][s][h*64+dk] (row-major A for final GEMM)
  const int b = bh >> 4, h = bh & 15;
#pragma unroll
  for (int mi = 0; mi < 2; ++mi)
#pragma unroll
    for (int r = 0; r < 4; ++r) {
      const int srow = qt * 128 + wave * 32 + mi * 16 + quad * 4 + r;
      const float linv = 1.0f / lrow[mi][r];
#pragma unroll
      for (int ni = 0; ni < 4; ++ni)
        Oa[((size_t)(b * S_ + srow) * H_ + h) * DK_ + ni * 16 + l16] =
            f2bf(o[mi][ni][r] * linv);
    }
}

// ---------------------------------------------------------------------------
extern "C" void kernel_launch(void* const* d_in, const int* in_sizes, int n_in,
                              void* d_out, int out_size, void* d_ws, size_t ws_size,
                              hipStream_t stream) {
  (void)in_sizes; (void)n_in; (void)out_size; (void)ws_size;
  const float* q  = (const float*)d_in[0];
  const float* k  = (const float*)d_in[1];
  const float* v  = (const float*)d_in[2];
  const float* Wq = (const float*)d_in[3];
  const float* Wk = (const float*)d_in[4];
  const float* Wv = (const float*)d_in[5];
  const float* Wo = (const float*)d_in[6];
  const float* qw = (const float*)d_in[7];
  const float* kw = (const float*)d_in[8];

  char* ws = (char*)d_ws;
  const size_t MB = 1u << 20;
  unsigned short* qb  = (unsigned short*)(ws + 0 * MB);    // 8 MB; later Qb
  unsigned short* kb  = (unsigned short*)(ws + 8 * MB);    // 8 MB; later Kb
  unsigned short* vb  = (unsigned short*)(ws + 16 * MB);   // 8 MB; later Vt
  unsigned short* wqb = (unsigned short*)(ws + 24 * MB);
  unsigned short* wkb = (unsigned short*)(ws + 26 * MB);
  unsigned short* wvb = (unsigned short*)(ws + 28 * MB);
  unsigned short* wob = (unsigned short*)(ws + 30 * MB);
  float*          Qh  = (float*)(ws + 32 * MB);            // 16 MB; later Ab
  float*          Kh  = (float*)(ws + 48 * MB);            // 16 MB
  unsigned short* Vh  = (unsigned short*)(ws + 64 * MB);   // 8 MB   (peak 72 MB)
  unsigned short* Qb  = qb;
  unsigned short* Kb  = kb;
  unsigned short* Vtb = vb;
  unsigned short* Ab  = (unsigned short*)Qh;

  cvt_bf16<<<dim3(4096, 7), 256, 0, stream>>>(q, k, v, Wq, Wk, Wv, Wo,
                                              qb, kb, vb, wqb, wkb, wvb, wob);

  const dim3 gg(D_ / 128, (B_ * S_) / 128);  // (8, 32)
  gemm_bt<0><<<gg, 256, 0, stream>>>(qb, wqb, Qh);
  gemm_bt<0><<<gg, 256, 0, stream>>>(kb, wkb, Kh);
  gemm_bt<1><<<gg, 256, 0, stream>>>(vb, wvb, Vh);

  rmsnorm_rope<<<dim3(B_ * H_ * S_ / 4, 2), 256, 0, stream>>>(Qh, Kh, Qb, Kb, qw, kw);
  transpose_v<<<dim3(S_ / 64, B_ * H_), 256, 0, stream>>>(Vh, Vtb);

  flash_mfma<<<dim3(S_ / 128, B_ * H_), 256, 0, stream>>>(Qb, Kb, Vtb, Ab);

  gemm_bt<2><<<gg, 256, 0, stream>>>(Ab, wob, (float*)d_out);
}

// Round 3
// 239.809 us; speedup vs baseline: 4.7632x; 1.4378x over previous
//
#include <hip/hip_runtime.h>
#include <hip/hip_bf16.h>
#include <math.h>

#define B_  2
#define S_  2048
#define D_  1024
#define H_  16
#define DK_ 64

typedef __attribute__((ext_vector_type(8))) short bf16x8;   // 8 bf16 = 4 VGPRs
typedef __attribute__((ext_vector_type(4))) float f32x4;

#define MFMA_BF16(a, b, c) __builtin_amdgcn_mfma_f32_16x16x32_bf16((a), (b), (c), 0, 0, 0)

// 0.125 (1/sqrt(DK)) * log2(e): folded into Q so P = v_exp(S^T) directly
#define QSCALE 0.18033688011112042f
// log2(500000)/32 for RoPE inv_freq = 2^(-j * this)
#define ROPE_L2 0.591611512f

// fp32 -> bf16 round-to-nearest-even
__device__ __forceinline__ unsigned short f2bf(float f) {
  unsigned int u = __float_as_uint(f);
  u += 0x7FFFu + ((u >> 16) & 1u);
  return (unsigned short)(u >> 16);
}

// async global->LDS, 16 B per lane; LDS dest = wave-uniform base + lane*16
__device__ __forceinline__ void gl_lds16(const void* g, void* l) {
  __builtin_amdgcn_global_load_lds(
      (const __attribute__((address_space(1))) void*)g,
      (__attribute__((address_space(3))) void*)l, 16, 0, 0);
}

// XOR-swizzled LDS index (ushort units). Rows are 64 ushorts = 128 B = 8
// 16B-chunks; chunk ^= row&7 makes both gl_lds16 staging (identity per-lane
// slots) and column-ish fragment reads conflict-free.
__device__ __forceinline__ int lsw(int row, int col) {
  return row * 64 + ((((col) >> 3) ^ (row & 7)) << 3) + (col & 7);
}

// ---------------------------------------------------------------------------
// fp32 -> bf16 conversion for q,k,v and the four weight matrices.
// ---------------------------------------------------------------------------
__global__ __launch_bounds__(256)
void cvt_bf16(const float* __restrict__ q, const float* __restrict__ k,
              const float* __restrict__ v, const float* __restrict__ wq,
              const float* __restrict__ wk, const float* __restrict__ wv,
              const float* __restrict__ wo,
              unsigned short* __restrict__ qb, unsigned short* __restrict__ kb,
              unsigned short* __restrict__ vb, unsigned short* __restrict__ wqb,
              unsigned short* __restrict__ wkb, unsigned short* __restrict__ wvb,
              unsigned short* __restrict__ wob) {
  const float* src; unsigned short* dst; int n;
  switch (blockIdx.y) {
    case 0: src = q;  dst = qb;  n = B_ * S_ * D_; break;
    case 1: src = k;  dst = kb;  n = B_ * S_ * D_; break;
    case 2: src = v;  dst = vb;  n = B_ * S_ * D_; break;
    case 3: src = wq; dst = wqb; n = D_ * D_; break;
    case 4: src = wk; dst = wkb; n = D_ * D_; break;
    case 5: src = wv; dst = wvb; n = D_ * D_; break;
    default: src = wo; dst = wob; n = D_ * D_; break;
  }
  const int i = (blockIdx.x * 256 + threadIdx.x) * 4;
  if (i >= n) return;
  float4 val = *(const float4*)&src[i];
  ushort4 r4;
  r4.x = f2bf(val.x); r4.y = f2bf(val.y); r4.z = f2bf(val.z); r4.w = f2bf(val.w);
  *(ushort4*)&dst[i] = r4;
}

// ---------------------------------------------------------------------------
// Fused QKV projection GEMM (blockIdx.z selects q/k/v) with fused epilogues:
//   z=0: RMSNorm + RoPE + QSCALE -> bf16 head-major [b][h][s][dk]
//   z=1: RMSNorm + RoPE          -> bf16 head-major
//   z=2: plain                   -> bf16 head-major
// 128x128 tile, BK=32, double-buffered global_load_lds staging (m97 style).
// The 128-col j-tile = 2 heads; wave's wn-half = exactly 1 head, so the
// per-row RMSNorm (dk=64) reduces over 4 acc regs + 16 l16 lanes (4 shuffles),
// and the RoPE rotate-half partner (dk +/- 32) is another acc reg of the SAME
// lane (ni +/- 2).
// ---------------------------------------------------------------------------
__global__ __launch_bounds__(256)
void gemm_qkv(const unsigned short* __restrict__ qa, const unsigned short* __restrict__ ka,
              const unsigned short* __restrict__ va,
              const unsigned short* __restrict__ wq, const unsigned short* __restrict__ wk,
              const unsigned short* __restrict__ wv,
              unsigned short* __restrict__ Qo, unsigned short* __restrict__ Ko,
              unsigned short* __restrict__ Vo,
              const float* __restrict__ qnw, const float* __restrict__ knw) {
  __shared__ unsigned short As[2][128 * 32];
  __shared__ unsigned short Bs[2][128 * 32];
  const int z = blockIdx.z;
  const unsigned short* A = (z == 0) ? qa : (z == 1) ? ka : va;
  const unsigned short* W = (z == 0) ? wq : (z == 1) ? wk : wv;
  unsigned short* out     = (z == 0) ? Qo : (z == 1) ? Ko : Vo;

  const int t = threadIdx.x, lane = t & 63, wave = t >> 6;
  const int l16 = lane & 15, quad = lane >> 4;
  const int wm = wave >> 1, wn = wave & 1;
  const int m0 = blockIdx.y * 128, j0 = blockIdx.x * 128;

  f32x4 acc[4][4];
#pragma unroll
  for (int i = 0; i < 4; ++i)
#pragma unroll
    for (int j = 0; j < 4; ++j) acc[i][j] = (f32x4)(0.0f);

  auto stage = [&](int kb, int buf) {
#pragma unroll
    for (int i = 0; i < 2; ++i) {
      const int c  = (wave * 2 + i) * 64 + lane;  // 16B chunk id, 0..511
      const int r  = c >> 2;                      // tile row 0..127
      const int co = (c & 3) * 8;                 // ushort offset in 32-wide row
      gl_lds16(&A[(size_t)(m0 + r) * D_ + kb + co], &As[buf][(wave * 2 + i) * 512]);
      gl_lds16(&W[(size_t)(j0 + r) * D_ + kb + co], &Bs[buf][(wave * 2 + i) * 512]);
    }
  };

  stage(0, 0);
  for (int kb = 0; kb < D_; kb += 32) {
    const int buf = (kb >> 5) & 1;
    __syncthreads();                 // staged buf ready (vmcnt drained at barrier)
    if (kb + 32 < D_) stage(kb + 32, buf ^ 1);

    bf16x8 af[4], bfr[4];
#pragma unroll
    for (int mi = 0; mi < 4; ++mi)
      af[mi] = *(const bf16x8*)&As[buf][(wm * 64 + mi * 16 + l16) * 32 + quad * 8];
#pragma unroll
    for (int ni = 0; ni < 4; ++ni)
      bfr[ni] = *(const bf16x8*)&Bs[buf][(wn * 64 + ni * 16 + l16) * 32 + quad * 8];
#pragma unroll
    for (int mi = 0; mi < 4; ++mi)
#pragma unroll
      for (int ni = 0; ni < 4; ++ni)
        acc[mi][ni] = MFMA_BF16(af[mi], bfr[ni], acc[mi][ni]);
  }

  // epilogue. C/D layout: col = l16 (n), row = quad*4 + reg (m).
  const int h = blockIdx.x * 2 + wn;   // one head per 64-col wave-half
  if (z == 2) {
#pragma unroll
    for (int mi = 0; mi < 4; ++mi) {
      const int rowb = m0 + wm * 64 + mi * 16 + quad * 4;
#pragma unroll
      for (int ni = 0; ni < 4; ++ni) {
        const int dk = ni * 16 + l16;
#pragma unroll
        for (int r = 0; r < 4; ++r) {
          const int rr = rowb + r;
          const int b = rr >> 11, s = rr & (S_ - 1);
          out[((size_t)(b * H_ + h) * S_ + s) * DK_ + dk] = f2bf(acc[mi][ni][r]);
        }
      }
    }
  } else {
    const float* nw = (z == 0) ? qnw : knw;
    const float sc  = (z == 0) ? QSCALE : 1.0f;
    float wv_[4];
#pragma unroll
    for (int ni = 0; ni < 4; ++ni) wv_[ni] = nw[ni * 16 + l16];
    const float invA = exp2f(-(float)l16 * ROPE_L2);         // j = l16
    const float invB = exp2f(-(float)(16 + l16) * ROPE_L2);  // j = 16 + l16
#pragma unroll
    for (int mi = 0; mi < 4; ++mi) {
#pragma unroll
      for (int r = 0; r < 4; ++r) {
        const int rowg = m0 + wm * 64 + mi * 16 + quad * 4 + r;
        const int b = rowg >> 11, s = rowg & (S_ - 1);
        float ss = 0.f;
#pragma unroll
        for (int ni = 0; ni < 4; ++ni) ss += acc[mi][ni][r] * acc[mi][ni][r];
#pragma unroll
        for (int m = 1; m < 16; m <<= 1) ss += __shfl_xor(ss, m);
        const float rms = rsqrtf(ss * (1.0f / DK_) + 1e-10f);
        float xn[4];
#pragma unroll
        for (int ni = 0; ni < 4; ++ni) xn[ni] = wv_[ni] * acc[mi][ni][r] * rms;
        const float fA = (float)s * invA, fB = (float)s * invB;
        const float cA = __cosf(fA) * sc, sA = __sinf(fA) * sc;
        const float cB = __cosf(fB) * sc, sB = __sinf(fB) * sc;
        float o0 = xn[0] * cA - xn[2] * sA;   // dk = l16       (<32, j=A)
        float o1 = xn[1] * cB - xn[3] * sB;   // dk = 16+l16    (<32, j=B)
        float o2 = xn[2] * cA + xn[0] * sA;   // dk = 32+l16    (>=32, j=A)
        float o3 = xn[3] * cB + xn[1] * sB;   // dk = 48+l16    (>=32, j=B)
        const size_t base = ((size_t)(b * H_ + h) * S_ + s) * DK_;
        out[base +  0 + l16] = f2bf(o0);
        out[base + 16 + l16] = f2bf(o1);
        out[base + 32 + l16] = f2bf(o2);
        out[base + 48 + l16] = f2bf(o3);
      }
    }
  }
}

// ---------------------------------------------------------------------------
// V transpose per head: bf16 [bh][s][dk] -> bf16 [bh][dk][s]
// ---------------------------------------------------------------------------
__global__ __launch_bounds__(256)
void transpose_v(const unsigned short* __restrict__ Vh, unsigned short* __restrict__ Vt) {
  __shared__ unsigned short tile[64 * 65];
  const int bh = blockIdx.y, s0 = blockIdx.x * 64;
  const int t = threadIdx.x;
  const size_t base = (size_t)bh * S_ * DK_;
#pragma unroll
  for (int i = 0; i < 2; ++i) {
    const int c = i * 256 + t;
    const int r = c >> 3, co = (c & 7) * 8;
    unsigned short tmp[8];
    *(bf16x8*)tmp = *(const bf16x8*)&Vh[base + (size_t)(s0 + r) * DK_ + co];
#pragma unroll
    for (int jj = 0; jj < 8; ++jj) tile[r * 65 + co + jj] = tmp[jj];
  }
  __syncthreads();
#pragma unroll
  for (int i = 0; i < 2; ++i) {
    const int c = i * 256 + t;
    const int dk = c >> 3, so = (c & 7) * 8;
    unsigned short tmp[8];
#pragma unroll
    for (int jj = 0; jj < 8; ++jj) tmp[jj] = tile[(so + jj) * 65 + dk];
    *(bf16x8*)&Vt[(size_t)bh * DK_ * S_ + (size_t)dk * S_ + s0 + so] = *(bf16x8*)tmp;
  }
}

// ---------------------------------------------------------------------------
// Flash attention v2: S^T = K Q^T (operand swap), no-max softmax (Q carries
// 0.125*log2e so P = v_exp(S^T)), l via ones-MFMA, single barrier per KV tile,
// double-buffered gl_lds16 K/V staging, XOR-swizzled LDS (conflict-free),
// packed b64 P-stores (P is wave-private: no second barrier).
// Grid: 512 1-D blocks; qt folded so co-resident pairs have equal work.
// ---------------------------------------------------------------------------
__global__ __launch_bounds__(256)
void flash2(const unsigned short* __restrict__ Q, const unsigned short* __restrict__ K,
            const unsigned short* __restrict__ Vt, unsigned short* __restrict__ Oa) {
  __shared__ unsigned short Ks[2][64 * 64];
  __shared__ unsigned short Vs[2][64 * 64];
  __shared__ unsigned short Ps[128 * 64];
  const int bx = blockIdx.x;
  const int qt = (bx < 256) ? (bx >> 5) : (15 - ((bx - 256) >> 5));  // balance
  const int bh = bx & 31;
  const int t = threadIdx.x, lane = t & 63, wave = t >> 6;
  const int l16 = lane & 15, quad = lane >> 4;
  const size_t hb = (size_t)bh * S_ * DK_;
  const unsigned short* Qh  = Q + hb;
  const unsigned short* Kh  = K + hb;
  const unsigned short* Vth = Vt + hb;      // [dk][s]

  // Q fragments (pre-scaled by QSCALE): lane holds q = base+l16, dk = quad*8..
  bf16x8 qf[2][2];
#pragma unroll
  for (int mi = 0; mi < 2; ++mi)
#pragma unroll
    for (int ks = 0; ks < 2; ++ks)
      qf[mi][ks] = *(const bf16x8*)
        &Qh[(size_t)(qt * 128 + wave * 32 + mi * 16 + l16) * DK_ + ks * 32 + quad * 8];

  bf16x8 ones;
#pragma unroll
  for (int j = 0; j < 8; ++j) ones[j] = (short)0x3F80;  // bf16 1.0

  f32x4 o[2][4], lacc[2];
#pragma unroll
  for (int mi = 0; mi < 2; ++mi) {
    lacc[mi] = (f32x4)(0.0f);
#pragma unroll
    for (int ni = 0; ni < 4; ++ni) o[mi][ni] = (f32x4)(0.0f);
  }

  // stage 16 rows/wave of K (and V^T) per tile; swizzled identity slots
  auto stage = [&](int kt, int bufi) {
#pragma unroll
    for (int i = 0; i < 2; ++i) {
      const int rbase = wave * 16 + i * 8;
      const int r = rbase + (lane >> 3);
      const int c = ((lane & 7) ^ (r & 7)) * 8;   // logical col (ushorts)
      gl_lds16(&Kh[(size_t)(kt * 64 + r) * DK_ + c], &Ks[bufi][rbase * 64]);
      gl_lds16(&Vth[(size_t)r * S_ + kt * 64 + c], &Vs[bufi][rbase * 64]);
    }
  };

  const int nkt = 2 * qt + 2;
  stage(0, 0);
  for (int kt = 0; kt < nkt; ++kt) {
    const int buf = kt & 1;
    __syncthreads();          // drains vmcnt: staged buf ready; buf^1 free
    if (kt + 1 < nkt) stage(kt + 1, buf ^ 1);

    // S^T = K Q^T : A = K-frag (m=kv), B = Q-frag (n=q)
    f32x4 sv[4][2];
#pragma unroll
    for (int kvi = 0; kvi < 4; ++kvi)
#pragma unroll
      for (int mi = 0; mi < 2; ++mi) sv[kvi][mi] = (f32x4)(0.0f);
#pragma unroll
    for (int ks = 0; ks < 2; ++ks) {
      bf16x8 ak[4];
#pragma unroll
      for (int kvi = 0; kvi < 4; ++kvi)
        ak[kvi] = *(const bf16x8*)&Ks[buf][lsw(kvi * 16 + l16, ks * 32 + quad * 8)];
#pragma unroll
      for (int kvi = 0; kvi < 4; ++kvi)
#pragma unroll
        for (int mi = 0; mi < 2; ++mi)
          sv[kvi][mi] = MFMA_BF16(ak[kvi], qf[mi][ks], sv[kvi][mi]);
    }

    // mask + exp2 + pack-truncate -> b64 stores (P wave-private)
    const bool diag = (kt >= 2 * qt);
#pragma unroll
    for (int kvi = 0; kvi < 4; ++kvi)
#pragma unroll
      for (int mi = 0; mi < 2; ++mi) {
        const int qg  = qt * 128 + wave * 32 + mi * 16 + l16;  // col = q
        const int kvb = kt * 64 + kvi * 16 + quad * 4;         // row = kv
        float p[4];
#pragma unroll
        for (int r = 0; r < 4; ++r) {
          float x = sv[kvi][mi][r];
          if (diag && (kvb + r) > qg) x = -INFINITY;
          p[r] = exp2f(x);                                      // v_exp_f32
        }
        const unsigned int d0 =
            (__float_as_uint(p[1]) & 0xFFFF0000u) | (__float_as_uint(p[0]) >> 16);
        const unsigned int d1 =
            (__float_as_uint(p[3]) & 0xFFFF0000u) | (__float_as_uint(p[2]) >> 16);
        *(uint2*)&Ps[lsw(wave * 32 + mi * 16 + l16, kvi * 16 + quad * 4)] =
            make_uint2(d0, d1);
      }
    asm volatile("s_waitcnt lgkmcnt(0)" ::: "memory");  // P visible to own wave

    // O += P V, l += P 1  (A = P[q][kv], B = V[kv][dk] / ones)
#pragma unroll
    for (int ks = 0; ks < 2; ++ks) {
      bf16x8 ap[2], bv[4];
#pragma unroll
      for (int mi = 0; mi < 2; ++mi)
        ap[mi] = *(const bf16x8*)&Ps[lsw(wave * 32 + mi * 16 + l16, ks * 32 + quad * 8)];
#pragma unroll
      for (int ni = 0; ni < 4; ++ni)
        bv[ni] = *(const bf16x8*)&Vs[buf][lsw(ni * 16 + l16, ks * 32 + quad * 8)];
#pragma unroll
      for (int mi = 0; mi < 2; ++mi) {
#pragma unroll
        for (int ni = 0; ni < 4; ++ni)
          o[mi][ni] = MFMA_BF16(ap[mi], bv[ni], o[mi][ni]);
        lacc[mi] = MFMA_BF16(ap[mi], ones, lacc[mi]);
      }
    }
  }

  // epilogue: O /= l, write bf16 row-major attn [b*S+s][h*64+dk]
  const int b = bh >> 4, h = bh & 15;
#pragma unroll
  for (int mi = 0; mi < 2; ++mi)
#pragma unroll
    for (int r = 0; r < 4; ++r) {
      const int srow = qt * 128 + wave * 32 + mi * 16 + quad * 4 + r;
      const float linv = 1.0f / lacc[mi][r];
#pragma unroll
      for (int ni = 0; ni < 4; ++ni)
        Oa[((size_t)(b * S_ + srow) * H_ + h) * DK_ + ni * 16 + l16] =
            f2bf(o[mi][ni][r] * linv);
    }
}

// ---------------------------------------------------------------------------
// Final output GEMM: fp32 row-major C = A(bf16) @ Wo(bf16)^T
// ---------------------------------------------------------------------------
__global__ __launch_bounds__(256)
void gemm_out(const unsigned short* __restrict__ A, const unsigned short* __restrict__ W,
              float* __restrict__ out) {
  __shared__ unsigned short As[2][128 * 32];
  __shared__ unsigned short Bs[2][128 * 32];
  const int t = threadIdx.x, lane = t & 63, wave = t >> 6;
  const int l16 = lane & 15, quad = lane >> 4;
  const int wm = wave >> 1, wn = wave & 1;
  const int m0 = blockIdx.y * 128, j0 = blockIdx.x * 128;

  f32x4 acc[4][4];
#pragma unroll
  for (int i = 0; i < 4; ++i)
#pragma unroll
    for (int j = 0; j < 4; ++j) acc[i][j] = (f32x4)(0.0f);

  auto stage = [&](int kb, int buf) {
#pragma unroll
    for (int i = 0; i < 2; ++i) {
      const int c  = (wave * 2 + i) * 64 + lane;
      const int r  = c >> 2;
      const int co = (c & 3) * 8;
      gl_lds16(&A[(size_t)(m0 + r) * D_ + kb + co], &As[buf][(wave * 2 + i) * 512]);
      gl_lds16(&W[(size_t)(j0 + r) * D_ + kb + co], &Bs[buf][(wave * 2 + i) * 512]);
    }
  };

  stage(0, 0);
  for (int kb = 0; kb < D_; kb += 32) {
    const int buf = (kb >> 5) & 1;
    __syncthreads();
    if (kb + 32 < D_) stage(kb + 32, buf ^ 1);

    bf16x8 af[4], bfr[4];
#pragma unroll
    for (int mi = 0; mi < 4; ++mi)
      af[mi] = *(const bf16x8*)&As[buf][(wm * 64 + mi * 16 + l16) * 32 + quad * 8];
#pragma unroll
    for (int ni = 0; ni < 4; ++ni)
      bfr[ni] = *(const bf16x8*)&Bs[buf][(wn * 64 + ni * 16 + l16) * 32 + quad * 8];
#pragma unroll
    for (int mi = 0; mi < 4; ++mi)
#pragma unroll
      for (int ni = 0; ni < 4; ++ni)
        acc[mi][ni] = MFMA_BF16(af[mi], bfr[ni], acc[mi][ni]);
  }

#pragma unroll
  for (int mi = 0; mi < 4; ++mi) {
    const int rowb = m0 + wm * 64 + mi * 16 + quad * 4;
#pragma unroll
    for (int ni = 0; ni < 4; ++ni) {
      const int col = j0 + wn * 64 + ni * 16 + l16;
#pragma unroll
      for (int r = 0; r < 4; ++r)
        out[(size_t)(rowb + r) * D_ + col] = acc[mi][ni][r];
    }
  }
}

// ---------------------------------------------------------------------------
extern "C" void kernel_launch(void* const* d_in, const int* in_sizes, int n_in,
                              void* d_out, int out_size, void* d_ws, size_t ws_size,
                              hipStream_t stream) {
  (void)in_sizes; (void)n_in; (void)out_size; (void)ws_size;
  const float* q  = (const float*)d_in[0];
  const float* k  = (const float*)d_in[1];
  const float* v  = (const float*)d_in[2];
  const float* Wq = (const float*)d_in[3];
  const float* Wk = (const float*)d_in[4];
  const float* Wv = (const float*)d_in[5];
  const float* Wo = (const float*)d_in[6];
  const float* qw = (const float*)d_in[7];
  const float* kw = (const float*)d_in[8];

  char* ws = (char*)d_ws;
  const size_t MB = 1u << 20;
  unsigned short* qb  = (unsigned short*)(ws + 0 * MB);    // bf16 inputs
  unsigned short* kb  = (unsigned short*)(ws + 8 * MB);
  unsigned short* vb  = (unsigned short*)(ws + 16 * MB);
  unsigned short* wqb = (unsigned short*)(ws + 24 * MB);
  unsigned short* wkb = (unsigned short*)(ws + 26 * MB);
  unsigned short* wvb = (unsigned short*)(ws + 28 * MB);
  unsigned short* wob = (unsigned short*)(ws + 30 * MB);
  unsigned short* Qb  = (unsigned short*)(ws + 32 * MB);   // normed+roped Q (scaled)
  unsigned short* Kb  = (unsigned short*)(ws + 40 * MB);   // normed+roped K
  unsigned short* Vh  = (unsigned short*)(ws + 48 * MB);   // V head-major
  unsigned short* Vtb = (unsigned short*)(ws + 56 * MB);   // V^T [bh][dk][s]
  unsigned short* Ab  = (unsigned short*)(ws + 64 * MB);   // attn out row-major

  cvt_bf16<<<dim3(4096, 7), 256, 0, stream>>>(q, k, v, Wq, Wk, Wv, Wo,
                                              qb, kb, vb, wqb, wkb, wvb, wob);

  gemm_qkv<<<dim3(D_ / 128, (B_ * S_) / 128, 3), 256, 0, stream>>>(
      qb, kb, vb, wqb, wkb, wvb, Qb, Kb, Vh, qw, kw);

  transpose_v<<<dim3(S_ / 64, B_ * H_), 256, 0, stream>>>(Vh, Vtb);

  flash2<<<512, 256, 0, stream>>>(Qb, Kb, Vtb, Ab);

  gemm_out<<<dim3(D_ / 128, (B_ * S_) / 128), 256, 0, stream>>>(Ab, wob, (float*)d_out);
}

// Round 4
// 215.260 us; speedup vs baseline: 5.3064x; 1.1140x over previous
//
#include <hip/hip_runtime.h>
#include <hip/hip_bf16.h>
#include <math.h>

#define B_  2
#define S_  2048
#define D_  1024
#define H_  16
#define DK_ 64

typedef __attribute__((ext_vector_type(8))) short bf16x8;   // 8 bf16 = 4 VGPRs
typedef __attribute__((ext_vector_type(4))) float f32x4;

#define MFMA_BF16(a, b, c) __builtin_amdgcn_mfma_f32_16x16x32_bf16((a), (b), (c), 0, 0, 0)

// 0.125 (1/sqrt(DK)) * log2(e): folded into Q so P = v_exp(S^T) directly
#define QSCALE 0.18033688011112042f
// log2(500000)/32 for RoPE inv_freq = 2^(-j * this)
#define ROPE_L2 0.591611512f

// fp32 -> bf16 round-to-nearest-even
__device__ __forceinline__ unsigned short f2bf(float f) {
  unsigned int u = __float_as_uint(f);
  u += 0x7FFFu + ((u >> 16) & 1u);
  return (unsigned short)(u >> 16);
}

// async global->LDS, 16 B per lane; LDS dest = wave-uniform base + lane*16
__device__ __forceinline__ void gl_lds16(const void* g, void* l) {
  __builtin_amdgcn_global_load_lds(
      (const __attribute__((address_space(1))) void*)g,
      (__attribute__((address_space(3))) void*)l, 16, 0, 0);
}

// XOR-swizzled LDS index (ushort units). Rows are 64 ushorts = 128 B = 8
// 16B-chunks; chunk ^= row&7 makes both gl_lds16 staging (identity per-lane
// slots) and column-ish fragment reads conflict-free.
__device__ __forceinline__ int lsw(int row, int col) {
  return row * 64 + ((((col) >> 3) ^ (row & 7)) << 3) + (col & 7);
}

// ---------------------------------------------------------------------------
// fp32 -> bf16 conversion for q,k,v and the four weight matrices.
// ---------------------------------------------------------------------------
__global__ __launch_bounds__(256)
void cvt_bf16(const float* __restrict__ q, const float* __restrict__ k,
              const float* __restrict__ v, const float* __restrict__ wq,
              const float* __restrict__ wk, const float* __restrict__ wv,
              const float* __restrict__ wo,
              unsigned short* __restrict__ qb, unsigned short* __restrict__ kb,
              unsigned short* __restrict__ vb, unsigned short* __restrict__ wqb,
              unsigned short* __restrict__ wkb, unsigned short* __restrict__ wvb,
              unsigned short* __restrict__ wob) {
  const float* src; unsigned short* dst; int n;
  switch (blockIdx.y) {
    case 0: src = q;  dst = qb;  n = B_ * S_ * D_; break;
    case 1: src = k;  dst = kb;  n = B_ * S_ * D_; break;
    case 2: src = v;  dst = vb;  n = B_ * S_ * D_; break;
    case 3: src = wq; dst = wqb; n = D_ * D_; break;
    case 4: src = wk; dst = wkb; n = D_ * D_; break;
    case 5: src = wv; dst = wvb; n = D_ * D_; break;
    default: src = wo; dst = wob; n = D_ * D_; break;
  }
  const int i = (blockIdx.x * 256 + threadIdx.x) * 4;
  if (i >= n) return;
  float4 val = *(const float4*)&src[i];
  ushort4 r4;
  r4.x = f2bf(val.x); r4.y = f2bf(val.y); r4.z = f2bf(val.z); r4.w = f2bf(val.w);
  *(ushort4*)&dst[i] = r4;
}

// ---------------------------------------------------------------------------
// Fused QKV projection GEMM (blockIdx.z selects q/k/v) with fused epilogues:
//   z=0: RMSNorm + RoPE + QSCALE -> bf16 head-major [b][h][s][dk]
//   z=1: RMSNorm + RoPE          -> bf16 head-major
//   z=2: plain                   -> bf16 V-TRANSPOSED [b][h][dk][s]
// 128x128 tile, BK=32, double-buffered global_load_lds staging (m97 style).
// The 128-col j-tile = 2 heads; wave's wn-half = exactly 1 head, so the
// per-row RMSNorm (dk=64) reduces over 4 acc regs + 16 l16 lanes (4 shuffles),
// and the RoPE rotate-half partner (dk +/- 32) is another acc reg of the SAME
// lane (ni +/- 2). V^T write: lane holds 4 consecutive s for fixed dk ->
// packed 8B stores (fuses the old transpose_v kernel).
// ---------------------------------------------------------------------------
__global__ __launch_bounds__(256)
void gemm_qkv(const unsigned short* __restrict__ qa, const unsigned short* __restrict__ ka,
              const unsigned short* __restrict__ va,
              const unsigned short* __restrict__ wq, const unsigned short* __restrict__ wk,
              const unsigned short* __restrict__ wv,
              unsigned short* __restrict__ Qo, unsigned short* __restrict__ Ko,
              unsigned short* __restrict__ Vto,
              const float* __restrict__ qnw, const float* __restrict__ knw) {
  __shared__ unsigned short As[2][128 * 32];
  __shared__ unsigned short Bs[2][128 * 32];
  const int z = blockIdx.z;
  const unsigned short* A = (z == 0) ? qa : (z == 1) ? ka : va;
  const unsigned short* W = (z == 0) ? wq : (z == 1) ? wk : wv;

  const int t = threadIdx.x, lane = t & 63, wave = t >> 6;
  const int l16 = lane & 15, quad = lane >> 4;
  const int wm = wave >> 1, wn = wave & 1;
  const int m0 = blockIdx.y * 128, j0 = blockIdx.x * 128;

  f32x4 acc[4][4];
#pragma unroll
  for (int i = 0; i < 4; ++i)
#pragma unroll
    for (int j = 0; j < 4; ++j) acc[i][j] = (f32x4)(0.0f);

  auto stage = [&](int kb, int buf) {
#pragma unroll
    for (int i = 0; i < 2; ++i) {
      const int c  = (wave * 2 + i) * 64 + lane;  // 16B chunk id, 0..511
      const int r  = c >> 2;                      // tile row 0..127
      const int co = (c & 3) * 8;                 // ushort offset in 32-wide row
      gl_lds16(&A[(size_t)(m0 + r) * D_ + kb + co], &As[buf][(wave * 2 + i) * 512]);
      gl_lds16(&W[(size_t)(j0 + r) * D_ + kb + co], &Bs[buf][(wave * 2 + i) * 512]);
    }
  };

  stage(0, 0);
  for (int kb = 0; kb < D_; kb += 32) {
    const int buf = (kb >> 5) & 1;
    __syncthreads();                 // staged buf ready (vmcnt drained at barrier)
    if (kb + 32 < D_) stage(kb + 32, buf ^ 1);

    bf16x8 af[4], bfr[4];
#pragma unroll
    for (int mi = 0; mi < 4; ++mi)
      af[mi] = *(const bf16x8*)&As[buf][(wm * 64 + mi * 16 + l16) * 32 + quad * 8];
#pragma unroll
    for (int ni = 0; ni < 4; ++ni)
      bfr[ni] = *(const bf16x8*)&Bs[buf][(wn * 64 + ni * 16 + l16) * 32 + quad * 8];
#pragma unroll
    for (int mi = 0; mi < 4; ++mi)
#pragma unroll
      for (int ni = 0; ni < 4; ++ni)
        acc[mi][ni] = MFMA_BF16(af[mi], bfr[ni], acc[mi][ni]);
  }

  // epilogue. C/D layout: col = l16 (n), row = quad*4 + reg (m).
  const int h = blockIdx.x * 2 + wn;   // one head per 64-col wave-half
  if (z == 2) {
    // V^T: [b][h][dk][s], packed 4-bf16 (8B) stores along s
#pragma unroll
    for (int mi = 0; mi < 4; ++mi) {
      const int rowb = m0 + wm * 64 + mi * 16 + quad * 4;
      const int b = rowb >> 11, s0 = rowb & (S_ - 1);
#pragma unroll
      for (int ni = 0; ni < 4; ++ni) {
        const int dk = ni * 16 + l16;
        const unsigned int u0 =
            (unsigned int)f2bf(acc[mi][ni][0]) | ((unsigned int)f2bf(acc[mi][ni][1]) << 16);
        const unsigned int u1 =
            (unsigned int)f2bf(acc[mi][ni][2]) | ((unsigned int)f2bf(acc[mi][ni][3]) << 16);
        *(uint2*)&Vto[((size_t)((b * H_ + h) * DK_ + dk)) * S_ + s0] = make_uint2(u0, u1);
      }
    }
  } else {
    unsigned short* out = (z == 0) ? Qo : Ko;
    const float* nw = (z == 0) ? qnw : knw;
    const float sc  = (z == 0) ? QSCALE : 1.0f;
    float wv_[4];
#pragma unroll
    for (int ni = 0; ni < 4; ++ni) wv_[ni] = nw[ni * 16 + l16];
    const float invA = exp2f(-(float)l16 * ROPE_L2);         // j = l16
    const float invB = exp2f(-(float)(16 + l16) * ROPE_L2);  // j = 16 + l16
#pragma unroll
    for (int mi = 0; mi < 4; ++mi) {
#pragma unroll
      for (int r = 0; r < 4; ++r) {
        const int rowg = m0 + wm * 64 + mi * 16 + quad * 4 + r;
        const int b = rowg >> 11, s = rowg & (S_ - 1);
        float ss = 0.f;
#pragma unroll
        for (int ni = 0; ni < 4; ++ni) ss += acc[mi][ni][r] * acc[mi][ni][r];
#pragma unroll
        for (int m = 1; m < 16; m <<= 1) ss += __shfl_xor(ss, m);
        const float rms = rsqrtf(ss * (1.0f / DK_) + 1e-10f);
        float xn[4];
#pragma unroll
        for (int ni = 0; ni < 4; ++ni) xn[ni] = wv_[ni] * acc[mi][ni][r] * rms;
        const float fA = (float)s * invA, fB = (float)s * invB;
        const float cA = __cosf(fA) * sc, sA = __sinf(fA) * sc;
        const float cB = __cosf(fB) * sc, sB = __sinf(fB) * sc;
        float o0 = xn[0] * cA - xn[2] * sA;   // dk = l16       (<32, j=A)
        float o1 = xn[1] * cB - xn[3] * sB;   // dk = 16+l16    (<32, j=B)
        float o2 = xn[2] * cA + xn[0] * sA;   // dk = 32+l16    (>=32, j=A)
        float o3 = xn[3] * cB + xn[1] * sB;   // dk = 48+l16    (>=32, j=B)
        const size_t base = ((size_t)(b * H_ + h) * S_ + s) * DK_;
        out[base +  0 + l16] = f2bf(o0);
        out[base + 16 + l16] = f2bf(o1);
        out[base + 32 + l16] = f2bf(o2);
        out[base + 48 + l16] = f2bf(o3);
      }
    }
  }
}

// ---------------------------------------------------------------------------
// Flash attention v3: 64-row Q-tiles, grid 1024 = 4 blocks/CU (LDS 40KB x 4
// = 160 KiB exactly), constant per-CU work via qt fold. S^T = K Q^T, no-max
// softmax (Q carries 0.125*log2e), l via ones-MFMA, single barrier per tile,
// double-buffered gl_lds16 staging, XOR-swizzled LDS, wave-private P.
// Co-resident set {c, c+256, c+512, c+768}: qt = {i, i+8, 31-i, 23-i} ->
// nkt sum = 66 for every CU (uniform causal work).
// ---------------------------------------------------------------------------
__global__ __launch_bounds__(256)
void flash3(const unsigned short* __restrict__ Q, const unsigned short* __restrict__ K,
            const unsigned short* __restrict__ Vt, unsigned short* __restrict__ Oa) {
  __shared__ unsigned short Ks[2][64 * 64];
  __shared__ unsigned short Vs[2][64 * 64];
  __shared__ unsigned short Ps[64 * 64];
  const int bx = blockIdx.x;
  const int idx = bx >> 5;
  const int qt = (idx < 16) ? idx : (47 - idx);   // balance across co-residents
  const int bh = bx & 31;
  const int t = threadIdx.x, lane = t & 63, wave = t >> 6;
  const int l16 = lane & 15, quad = lane >> 4;
  const size_t hb = (size_t)bh * S_ * DK_;
  const unsigned short* Qh  = Q + hb;
  const unsigned short* Kh  = K + hb;
  const unsigned short* Vth = Vt + hb;      // [dk][s]

  // Q fragments (pre-scaled): wave owns q rows qt*64 + wave*16 .. +15
  bf16x8 qf[2];
#pragma unroll
  for (int ks = 0; ks < 2; ++ks)
    qf[ks] = *(const bf16x8*)
      &Qh[(size_t)(qt * 64 + wave * 16 + l16) * DK_ + ks * 32 + quad * 8];

  bf16x8 ones;
#pragma unroll
  for (int j = 0; j < 8; ++j) ones[j] = (short)0x3F80;  // bf16 1.0

  f32x4 o[4], lacc;
  lacc = (f32x4)(0.0f);
#pragma unroll
  for (int ni = 0; ni < 4; ++ni) o[ni] = (f32x4)(0.0f);

  // stage 16 rows/wave of K (and V^T) per tile; swizzled identity slots
  auto stage = [&](int kt, int bufi) {
#pragma unroll
    for (int i = 0; i < 2; ++i) {
      const int rbase = wave * 16 + i * 8;
      const int r = rbase + (lane >> 3);
      const int c = ((lane & 7) ^ (r & 7)) * 8;   // logical col (ushorts)
      gl_lds16(&Kh[(size_t)(kt * 64 + r) * DK_ + c], &Ks[bufi][rbase * 64]);
      gl_lds16(&Vth[(size_t)r * S_ + kt * 64 + c], &Vs[bufi][rbase * 64]);
    }
  };

  const int nkt = qt + 1;
  stage(0, 0);
  for (int kt = 0; kt < nkt; ++kt) {
    const int buf = kt & 1;
    __syncthreads();          // drains vmcnt: staged buf ready; buf^1 free
    if (kt + 1 < nkt) stage(kt + 1, buf ^ 1);

    // S^T = K Q^T : A = K-frag (m=kv), B = Q-frag (n=q)
    f32x4 sv[4];
#pragma unroll
    for (int kvi = 0; kvi < 4; ++kvi) sv[kvi] = (f32x4)(0.0f);
#pragma unroll
    for (int ks = 0; ks < 2; ++ks) {
      bf16x8 ak[4];
#pragma unroll
      for (int kvi = 0; kvi < 4; ++kvi)
        ak[kvi] = *(const bf16x8*)&Ks[buf][lsw(kvi * 16 + l16, ks * 32 + quad * 8)];
#pragma unroll
      for (int kvi = 0; kvi < 4; ++kvi)
        sv[kvi] = MFMA_BF16(ak[kvi], qf[ks], sv[kvi]);
    }

    // exp2 (+ mask only on the single diagonal tile; wave-uniform branch)
    float p[4][4];
    if (kt == qt) {
      const int qg = qt * 64 + wave * 16 + l16;
#pragma unroll
      for (int kvi = 0; kvi < 4; ++kvi)
#pragma unroll
        for (int r = 0; r < 4; ++r) {
          float x = sv[kvi][r];
          if ((kt * 64 + kvi * 16 + quad * 4 + r) > qg) x = -INFINITY;
          p[kvi][r] = exp2f(x);
        }
    } else {
#pragma unroll
      for (int kvi = 0; kvi < 4; ++kvi)
#pragma unroll
        for (int r = 0; r < 4; ++r) p[kvi][r] = exp2f(sv[kvi][r]);
    }

    // pack-truncate -> b64 stores (P wave-private: q rows wave*16..+15)
#pragma unroll
    for (int kvi = 0; kvi < 4; ++kvi) {
      const unsigned int d0 =
          (__float_as_uint(p[kvi][1]) & 0xFFFF0000u) | (__float_as_uint(p[kvi][0]) >> 16);
      const unsigned int d1 =
          (__float_as_uint(p[kvi][3]) & 0xFFFF0000u) | (__float_as_uint(p[kvi][2]) >> 16);
      *(uint2*)&Ps[lsw(wave * 16 + l16, kvi * 16 + quad * 4)] = make_uint2(d0, d1);
    }
    asm volatile("s_waitcnt lgkmcnt(0)" ::: "memory");  // P visible to own wave

    // O += P V, l += P 1  (A = P[q][kv], B = V[kv][dk] / ones)
#pragma unroll
    for (int ks = 0; ks < 2; ++ks) {
      bf16x8 ap, bv[4];
      ap = *(const bf16x8*)&Ps[lsw(wave * 16 + l16, ks * 32 + quad * 8)];
#pragma unroll
      for (int ni = 0; ni < 4; ++ni)
        bv[ni] = *(const bf16x8*)&Vs[buf][lsw(ni * 16 + l16, ks * 32 + quad * 8)];
#pragma unroll
      for (int ni = 0; ni < 4; ++ni)
        o[ni] = MFMA_BF16(ap, bv[ni], o[ni]);
      lacc = MFMA_BF16(ap, ones, lacc);
    }
  }

  // epilogue: O /= l, write bf16 row-major attn [b*S+s][h*64+dk]
  const int b = bh >> 4, h = bh & 15;
#pragma unroll
  for (int r = 0; r < 4; ++r) {
    const int srow = qt * 64 + wave * 16 + quad * 4 + r;
    const float linv = 1.0f / lacc[r];
#pragma unroll
    for (int ni = 0; ni < 4; ++ni)
      Oa[((size_t)(b * S_ + srow) * H_ + h) * DK_ + ni * 16 + l16] =
          f2bf(o[ni][r] * linv);
  }
}

// ---------------------------------------------------------------------------
// Final output GEMM: fp32 row-major C = A(bf16) @ Wo(bf16)^T
// ---------------------------------------------------------------------------
__global__ __launch_bounds__(256)
void gemm_out(const unsigned short* __restrict__ A, const unsigned short* __restrict__ W,
              float* __restrict__ out) {
  __shared__ unsigned short As[2][128 * 32];
  __shared__ unsigned short Bs[2][128 * 32];
  const int t = threadIdx.x, lane = t & 63, wave = t >> 6;
  const int l16 = lane & 15, quad = lane >> 4;
  const int wm = wave >> 1, wn = wave & 1;
  const int m0 = blockIdx.y * 128, j0 = blockIdx.x * 128;

  f32x4 acc[4][4];
#pragma unroll
  for (int i = 0; i < 4; ++i)
#pragma unroll
    for (int j = 0; j < 4; ++j) acc[i][j] = (f32x4)(0.0f);

  auto stage = [&](int kb, int buf) {
#pragma unroll
    for (int i = 0; i < 2; ++i) {
      const int c  = (wave * 2 + i) * 64 + lane;
      const int r  = c >> 2;
      const int co = (c & 3) * 8;
      gl_lds16(&A[(size_t)(m0 + r) * D_ + kb + co], &As[buf][(wave * 2 + i) * 512]);
      gl_lds16(&W[(size_t)(j0 + r) * D_ + kb + co], &Bs[buf][(wave * 2 + i) * 512]);
    }
  };

  stage(0, 0);
  for (int kb = 0; kb < D_; kb += 32) {
    const int buf = (kb >> 5) & 1;
    __syncthreads();
    if (kb + 32 < D_) stage(kb + 32, buf ^ 1);

    bf16x8 af[4], bfr[4];
#pragma unroll
    for (int mi = 0; mi < 4; ++mi)
      af[mi] = *(const bf16x8*)&As[buf][(wm * 64 + mi * 16 + l16) * 32 + quad * 8];
#pragma unroll
    for (int ni = 0; ni < 4; ++ni)
      bfr[ni] = *(const bf16x8*)&Bs[buf][(wn * 64 + ni * 16 + l16) * 32 + quad * 8];
#pragma unroll
    for (int mi = 0; mi < 4; ++mi)
#pragma unroll
      for (int ni = 0; ni < 4; ++ni)
        acc[mi][ni] = MFMA_BF16(af[mi], bfr[ni], acc[mi][ni]);
  }

#pragma unroll
  for (int mi = 0; mi < 4; ++mi) {
    const int rowb = m0 + wm * 64 + mi * 16 + quad * 4;
#pragma unroll
    for (int ni = 0; ni < 4; ++ni) {
      const int col = j0 + wn * 64 + ni * 16 + l16;
#pragma unroll
      for (int r = 0; r < 4; ++r)
        out[(size_t)(rowb + r) * D_ + col] = acc[mi][ni][r];
    }
  }
}

// ---------------------------------------------------------------------------
extern "C" void kernel_launch(void* const* d_in, const int* in_sizes, int n_in,
                              void* d_out, int out_size, void* d_ws, size_t ws_size,
                              hipStream_t stream) {
  (void)in_sizes; (void)n_in; (void)out_size; (void)ws_size;
  const float* q  = (const float*)d_in[0];
  const float* k  = (const float*)d_in[1];
  const float* v  = (const float*)d_in[2];
  const float* Wq = (const float*)d_in[3];
  const float* Wk = (const float*)d_in[4];
  const float* Wv = (const float*)d_in[5];
  const float* Wo = (const float*)d_in[6];
  const float* qw = (const float*)d_in[7];
  const float* kw = (const float*)d_in[8];

  char* ws = (char*)d_ws;
  const size_t MB = 1u << 20;
  unsigned short* qb  = (unsigned short*)(ws + 0 * MB);    // bf16 inputs
  unsigned short* kb  = (unsigned short*)(ws + 8 * MB);
  unsigned short* vb  = (unsigned short*)(ws + 16 * MB);
  unsigned short* wqb = (unsigned short*)(ws + 24 * MB);
  unsigned short* wkb = (unsigned short*)(ws + 26 * MB);
  unsigned short* wvb = (unsigned short*)(ws + 28 * MB);
  unsigned short* wob = (unsigned short*)(ws + 30 * MB);
  unsigned short* Qb  = (unsigned short*)(ws + 32 * MB);   // normed+roped Q (scaled)
  unsigned short* Kb  = (unsigned short*)(ws + 40 * MB);   // normed+roped K
  unsigned short* Vtb = (unsigned short*)(ws + 48 * MB);   // V^T [bh][dk][s]
  unsigned short* Ab  = (unsigned short*)(ws + 56 * MB);   // attn out row-major

  cvt_bf16<<<dim3(4096, 7), 256, 0, stream>>>(q, k, v, Wq, Wk, Wv, Wo,
                                              qb, kb, vb, wqb, wkb, wvb, wob);

  gemm_qkv<<<dim3(D_ / 128, (B_ * S_) / 128, 3), 256, 0, stream>>>(
      qb, kb, vb, wqb, wkb, wvb, Qb, Kb, Vtb, qw, kw);

  flash3<<<1024, 256, 0, stream>>>(Qb, Kb, Vtb, Ab);

  gemm_out<<<dim3(D_ / 128, (B_ * S_) / 128), 256, 0, stream>>>(Ab, wob, (float*)d_out);
}